// Round 3
// baseline (1547.711 us; speedup 1.0000x reference)
//
#include <hip/hip_runtime.h>

typedef unsigned short u16;
typedef __attribute__((ext_vector_type(8))) __bf16 bf16x8;
typedef __attribute__((ext_vector_type(4))) float f32x4;
typedef __attribute__((ext_vector_type(16))) float f32x16;

__device__ __forceinline__ u16 f2bf(float x) {
    union { float f; unsigned int u; } v; v.f = x;
    unsigned int r = v.u + 0x7fffu + ((v.u >> 16) & 1u);
    return (u16)(r >> 16);
}

// ---------------- one-shot conversion of the 3 weight matrices to bf16 ----------------
__global__ void cvt_w3(const float* __restrict__ a, const float* __restrict__ b,
                       const float* __restrict__ c, u16* __restrict__ dst) {
    int i = blockIdx.x * blockDim.x + threadIdx.x;   // 0..393215 ; 8 elems each
    int wsel = i >> 17;                              // 131072 eight-groups per W
    int j = i & 131071;
    const float* src = (wsel == 0) ? a : ((wsel == 1) ? b : c);
    const float4* s = (const float4*)src + (size_t)j * 2;
    float4 x = s[0], y = s[1];
    union { u16 u[8]; uint4 v; } o;
    o.u[0] = f2bf(x.x); o.u[1] = f2bf(x.y); o.u[2] = f2bf(x.z); o.u[3] = f2bf(x.w);
    o.u[4] = f2bf(y.x); o.u[5] = f2bf(y.y); o.u[6] = f2bf(y.z); o.u[7] = f2bf(y.w);
    *((uint4*)dst + (size_t)wsel * 131072 + j) = o.v;
}

// ---------------- QKV projection GEMM ----------------
// C[M=40960][N=3072] = X[M][1024](fp32, converted in staging) @ W^T(bf16) + bias
// 128x128 tile, BK=64, register double-buffer, 4 waves of 64x64, 16x16x32 MFMA.
// Output Y head-major: [b][h][t in {q,k,v}][s(20)][d(64)] bf16.
// XCD swizzle: 24 N-blocks sharing an M-band run consecutively on one XCD.
__global__ __launch_bounds__(256) void gemm_qkv(
    const float* __restrict__ X, const u16* __restrict__ W,
    const float* __restrict__ bQ, const float* __restrict__ bK,
    const float* __restrict__ bV, u16* __restrict__ Y)
{
    __shared__ __align__(16) u16 As[8192];   // 128 rows x 64 k ; chunk c = kg*128+row (kg 0..7, 8 elems)
    __shared__ __align__(16) u16 Bs[8192];
    const int tid = threadIdx.x;
    const int w = tid >> 6, lane = tid & 63;
    const int wm = (w >> 1) << 6, wn = (w & 1) << 6;
    const int l15 = lane & 15, kq = lane >> 4;

    // XCD-aware remap (8 XCDs, id%8 round-robin heuristic; bijective on 7680)
    const int id = blockIdx.y * 24 + blockIdx.x;
    const int xcd = id & 7, sl = id >> 3;
    const int xb = sl % 24, yb = (sl / 24) * 8 + xcd;
    const size_t mBase = (size_t)yb << 7;
    const int nBase = xb << 7;

    // staging: thread covers chunks {tid, 256+tid, 512+tid, 768+tid} -> kg = kg0 + 2t, row = tid&127
    const int row = tid & 127, kg0 = tid >> 7;
    const float* xp = X + (mBase + row) * 1024 + kg0 * 8;
    const u16*  wp = W + (size_t)(nBase + row) * 1024 + kg0 * 8;
    char* aBase = (char*)As + kg0 * 2048 + row * 16;
    char* bBase = (char*)Bs + kg0 * 2048 + row * 16;

    f32x4 acc[4][4];
    for (int mi = 0; mi < 4; ++mi)
        for (int ni = 0; ni < 4; ++ni)
            for (int r = 0; r < 4; ++r) acc[mi][ni][r] = 0.f;

    float4 ax[4][2]; uint4 bx[4];
#pragma unroll
    for (int t = 0; t < 4; ++t) {
        ax[t][0] = *(const float4*)(xp + t * 16);
        ax[t][1] = *(const float4*)(xp + t * 16 + 4);
        bx[t]    = *(const uint4*)(wp + t * 16);
    }

    for (int k0 = 0; k0 < 1024; k0 += 64) {
        __syncthreads();                       // previous iter's ds_reads complete
#pragma unroll
        for (int t = 0; t < 4; ++t) {
            union { u16 u[8]; uint4 v; } o;
            o.u[0] = f2bf(ax[t][0].x); o.u[1] = f2bf(ax[t][0].y);
            o.u[2] = f2bf(ax[t][0].z); o.u[3] = f2bf(ax[t][0].w);
            o.u[4] = f2bf(ax[t][1].x); o.u[5] = f2bf(ax[t][1].y);
            o.u[6] = f2bf(ax[t][1].z); o.u[7] = f2bf(ax[t][1].w);
            *(uint4*)(aBase + t * 4096) = o.v;
            *(uint4*)(bBase + t * 4096) = bx[t];
        }
        __syncthreads();                       // writes visible
        const int kn = (k0 + 64 < 1024) ? (k0 + 64) : 0;   // clamped prefetch (last iter wasted, cached)
#pragma unroll
        for (int t = 0; t < 4; ++t) {
            ax[t][0] = *(const float4*)(xp + kn + t * 16);
            ax[t][1] = *(const float4*)(xp + kn + t * 16 + 4);
            bx[t]    = *(const uint4*)(wp + kn + t * 16);
        }
#pragma unroll
        for (int ks = 0; ks < 2; ++ks) {
            const int kgo = (ks * 4 + kq) * 2048;
            bf16x8 af[4], bfr[4];
#pragma unroll
            for (int mi = 0; mi < 4; ++mi)
                af[mi] = *(const bf16x8*)((char*)As + kgo + (wm + mi * 16 + l15) * 16);
#pragma unroll
            for (int ni = 0; ni < 4; ++ni)
                bfr[ni] = *(const bf16x8*)((char*)Bs + kgo + (wn + ni * 16 + l15) * 16);
#pragma unroll
            for (int mi = 0; mi < 4; ++mi)
#pragma unroll
                for (int ni = 0; ni < 4; ++ni)
                    acc[mi][ni] = __builtin_amdgcn_mfma_f32_16x16x32_bf16(af[mi], bfr[ni], acc[mi][ni], 0, 0, 0);
        }
    }

    // epilogue: bias + bf16 store into head-major Y
    const int third = nBase >> 10;
    const float* bias = (third == 0) ? bQ : ((third == 1) ? bK : bV);
    const int bcol = (nBase & 1023) + wn + l15;
    float bv[4];
#pragma unroll
    for (int ni = 0; ni < 4; ++ni) bv[ni] = bias[bcol + ni * 16];
#pragma unroll
    for (int mi = 0; mi < 4; ++mi) {
        const int m0 = (int)mBase + wm + mi * 16 + kq * 4;
#pragma unroll
        for (int r = 0; r < 4; ++r) {
            const unsigned int mrow = (unsigned int)(m0 + r);
            const unsigned int bb = mrow / 20u;
            const unsigned int ss = mrow - bb * 20u;
#pragma unroll
            for (int ni = 0; ni < 4; ++ni) {
                const int col = nBase + wn + ni * 16 + l15;
                const int t3 = col >> 10, rem = col & 1023;
                const int head = rem >> 6, dd = rem & 63;
                Y[(((size_t)bb * 16 + head) * 3 + t3) * 1280 + ss * 64 + dd] =
                    f2bf(acc[mi][ni][r] + bv[ni]);
            }
        }
    }
}

// ---------------- fused decay attention: one wave per (batch, head) ----------------
// Y head-major: per (b,h): q[20][64] | k[20][64] | v[20][64] contiguous (1280 elems each).
__global__ __launch_bounds__(256) void attn_dec(
    const u16* __restrict__ Y, const int* __restrict__ lenp, float* __restrict__ out)
{
    __shared__ __align__(16) u16 coefLds[4][1024];   // [32][32] bf16 per wave
    __shared__ __align__(16) u16 vLds[4][1280];      // [20][64] bf16 per wave
    const int tid = threadIdx.x;
    const int w = tid >> 6, lane = tid & 63;
    const int u = blockIdx.x * 4 + w;                // u = b*16 + h
    const int b = u >> 4, h = u & 15;
    const int L = lenp[b];
    const int j32 = lane & 31, hw = lane >> 5;
    const int m19 = (j32 < 19) ? j32 : 19;

    const u16* qb = Y + (size_t)u * 3840;
    const u16* kb = qb + 1280;
    const u16* vb = qb + 2560;

    // QK^T : rows m = lane&31 (clamped), K over d=0..63 in 4 MFMAs
    f32x16 s;
    for (int r = 0; r < 16; ++r) s[r] = 0.f;
#pragma unroll
    for (int kc = 0; kc < 4; ++kc) {
        const int off = kc * 16 + hw * 8;
        bf16x8 aq = *(const bf16x8*)(qb + m19 * 64 + off);
        bf16x8 bk = *(const bf16x8*)(kb + m19 * 64 + off);
        s = __builtin_amdgcn_mfma_f32_32x32x16_bf16(aq, bk, s, 0, 0, 0);
    }

    // stage v[20][64] into LDS — now fully contiguous
#pragma unroll
    for (int t = 0; t < 3; ++t) {
        int c = t * 64 + lane;
        if (c < 160)
            *(uint4*)&vLds[w][c * 8] = *(const uint4*)(vb + c * 8);
    }

    // exp, mask, rowsum (32-lane butterfly), coef = attn + Md, store to LDS in A-layout
#pragma unroll
    for (int r = 0; r < 16; ++r) {
        int i = (r & 3) + ((r >> 2) << 3) + (hw << 2);
        float ev = (i < 20 && j32 < L) ? __expf(s[r] * 0.125f) : 0.f;
        float sum = ev;
#pragma unroll
        for (int o = 1; o < 32; o <<= 1) sum += __shfl_xor(sum, o, 32);
        float coef = ev / (sum + 1e-8f);
        if (i < 20 && j32 < 20) coef -= (float)((i > j32) ? (i - j32) : (j32 - i));
        if (i >= 20 || j32 >= 20) coef = 0.f;
        coefLds[w][i * 32 + j32] = f2bf(coef);
    }
    __syncthreads();

    // PV: D[i][d] = sum_j coef[i][j] v[j][d] ; N=64 as two 32-col tiles
    f32x16 o0, o1;
    for (int r = 0; r < 16; ++r) { o0[r] = 0.f; o1[r] = 0.f; }
#pragma unroll
    for (int kc = 0; kc < 2; ++kc) {
        bf16x8 ac = *(const bf16x8*)&coefLds[w][j32 * 32 + kc * 16 + hw * 8];
        bf16x8 bv0, bv1;
#pragma unroll
        for (int jj = 0; jj < 8; ++jj) {
            int j = kc * 16 + hw * 8 + jj;
            int jc = (j < 19) ? j : 19;     // coef=0 for j>=20; stay in-bounds
            bv0[jj] = *(const __bf16*)&vLds[w][jc * 64 + j32];
            bv1[jj] = *(const __bf16*)&vLds[w][jc * 64 + 32 + j32];
        }
        o0 = __builtin_amdgcn_mfma_f32_32x32x16_bf16(ac, bv0, o0, 0, 0, 0);
        o1 = __builtin_amdgcn_mfma_f32_32x32x16_bf16(ac, bv1, o1, 0, 0, 0);
    }

#pragma unroll
    for (int r = 0; r < 16; ++r) {
        int i = (r & 3) + ((r >> 2) << 3) + (hw << 2);
        if (i < 20) {
            size_t ro = ((size_t)b * 20 + i) * 1024 + h * 64 + j32;
            out[ro] = o0[r];
            out[ro + 32] = o1[r];
        }
    }
}

// ---------------- driver ----------------
extern "C" void kernel_launch(void* const* d_in, const int* in_sizes, int n_in,
                              void* d_out, int out_size, void* d_ws, size_t ws_size,
                              hipStream_t stream) {
    const float* Q   = (const float*)d_in[0];
    const float* W_Q = (const float*)d_in[1];
    const float* b_Q = (const float*)d_in[2];
    const float* W_K = (const float*)d_in[3];
    const float* b_K = (const float*)d_in[4];
    const float* W_V = (const float*)d_in[5];
    const float* b_V = (const float*)d_in[6];
    const int*   len = (const int*)d_in[7];
    float* out = (float*)d_out;

    // ws layout (bf16): Wbf[3072*1024] | Yq[2048*16*3*20*64]  = 6291456 + 251658240 B
    if (ws_size < 257949696ull) return;   // known false (round-2 proved ws >= 342 MB)
    u16* Wbf = (u16*)d_ws;
    u16* Yq  = Wbf + 3145728;

    cvt_w3<<<1536, 256, 0, stream>>>(W_Q, W_K, W_V, Wbf);
    gemm_qkv<<<dim3(24, 320), 256, 0, stream>>>(Q, Wbf, b_Q, b_K, b_V, Yq);
    attn_dec<<<8192, 256, 0, stream>>>(Yq, len, out);
}